// Round 11
// baseline (569.069 us; speedup 1.0000x reference)
//
#include <hip/hip_runtime.h>

// Generalized Lotka-Volterra, RK4, D=64, batch 2048, 255 steps,
// trajectory out (batch, 256, 64) fp32 — MFMA, zero-shuffle feedback,
// TWO independent RK4 chains per wave (ILP-2 latency hiding).
//
// R8 (270us) was latency-bound: 1 wave/SIMD, ~1900 stall cyc/step in the
// pkrtz->MFMA->epilogue->combine chain, occupancy structurally capped at
// 128 waves. This round: each wave integrates TWO 16-batch groups (G0, G1)
// with fully independent fevals interleaved at statement level — chain B's
// work fills chain A's latency gaps. af (E fragments) and rl are shared, so
// the marginal cost is only the second state set (~64 VGPRs).
//
// Everything else is R8-exact (each piece the verified best of rounds 7-10):
//  - need-layout x[t][q] = X[batch p][d(t,g,q)], d = 32(t>>1)+8g+4(t&1)+q
//  - E_perm rows: position 16t+4g+q holds row d -> MFMA C-output lands
//    exactly where the next B-fragment needs it (zero-shuffle feedback)
//  - A[row=p][k=8g+j], B[k=8g+j][col=p], C[row=4g+q][col=p] (HW-verified)
//  - chained MFMA pairs (R9/R10's split accumulators: no gain, more regs)
//  - "+v" pins on af (R10's "+a" pin: -48%, ISel copies AGPR->VGPR per use)
//  - LDS-transpose coalesced store (R9's direct stores: +64% WRITE_SIZE)

constexpr int D  = 64;    // state dimension
constexpr int NT = 256;   // trajectory length (255 RK4 steps)
constexpr int BW = 32;    // batch elements per wave (2 groups of 16)

typedef _Float16 f16x8 __attribute__((ext_vector_type(8)));
typedef float    f32x4 __attribute__((ext_vector_type(4)));

__device__ __forceinline__ uint32_t pkrtz(float lo, float hi) {
    return __builtin_bit_cast(uint32_t, __builtin_amdgcn_cvt_pkrtz(lo, hi));
}
__device__ __forceinline__ f32x4 vsplat(float v) {
    return (f32x4){v, v, v, v};
}

// Pack need-layout state XT (f32x4[4]) into two f16x8 B-fragments.
#define PACK2(XT, BF0, BF1)                                                   \
    do {                                                                      \
        union { uint32_t u[4]; f16x8 v; } u0_, u1_;                           \
        u0_.u[0] = pkrtz(XT[0][0], XT[0][1]);                                 \
        u0_.u[1] = pkrtz(XT[0][2], XT[0][3]);                                 \
        u0_.u[2] = pkrtz(XT[1][0], XT[1][1]);                                 \
        u0_.u[3] = pkrtz(XT[1][2], XT[1][3]);                                 \
        u1_.u[0] = pkrtz(XT[2][0], XT[2][1]);                                 \
        u1_.u[1] = pkrtz(XT[2][2], XT[2][3]);                                 \
        u1_.u[2] = pkrtz(XT[3][0], XT[3][1]);                                 \
        u1_.u[3] = pkrtz(XT[3][2], XT[3][3]);                                 \
        BF0 = u0_.v; BF1 = u1_.v;                                             \
    } while (0)

// Dual feval: FA = fA(XA), FB = fB(XB), two independent chains interleaved.
// f(X) = X .* ((r - X) + E@X); E-term via chained MFMA pair per tile.
#define FEVAL2(XA, FA, XB, FB)                                                \
    do {                                                                      \
        f16x8 bfA0, bfA1, bfB0, bfB1;                                         \
        PACK2(XA, bfA0, bfA1);                                                \
        PACK2(XB, bfB0, bfB1);                                                \
        _Pragma("unroll")                                                     \
        for (int t_ = 0; t_ < 4; ++t_) {                                      \
            f32x4 cA_ = rl[t_] - XA[t_];                                      \
            f32x4 cB_ = rl[t_] - XB[t_];                                      \
            cA_ = __builtin_amdgcn_mfma_f32_16x16x32_f16(af[t_][0], bfA0, cA_, 0, 0, 0); \
            cB_ = __builtin_amdgcn_mfma_f32_16x16x32_f16(af[t_][0], bfB0, cB_, 0, 0, 0); \
            cA_ = __builtin_amdgcn_mfma_f32_16x16x32_f16(af[t_][1], bfA1, cA_, 0, 0, 0); \
            cB_ = __builtin_amdgcn_mfma_f32_16x16x32_f16(af[t_][1], bfB1, cB_, 0, 0, 0); \
            FA[t_] = XA[t_] * cA_;                                            \
            FB[t_] = XB[t_] * cB_;                                            \
        }                                                                     \
    } while (0)

// RK4 stage combines for one chain (S = running sum, XS = next stage input).
#define COMB(X, S, XS, K, WS, WX)                                             \
    _Pragma("unroll")                                                         \
    for (int t_ = 0; t_ < 4; ++t_) {                                          \
        S[t_]  = S[t_] + vsplat(WS) * K[t_];                                  \
        XS[t_] = X[t_] + vsplat(WX) * K[t_];                                  \
    }

// Coalesce step TS of both groups through LDS (pad-17 rows, <=2-way banks).
#define STORE_STEP(TS)                                                        \
    do {                                                                      \
        _Pragma("unroll")                                                     \
        for (int t_ = 0; t_ < 4; ++t_)                                        \
            _Pragma("unroll")                                                 \
            for (int q_ = 0; q_ < 4; ++q_) {                                  \
                xT[0][(dbase[t_] + q_) * 17 + p] = xA[t_][q_];                \
                xT[1][(dbase[t_] + q_) * 17 + p] = xB[t_][q_];                \
            }                                                                 \
        asm volatile("s_waitcnt lgkmcnt(0)" ::: "memory");                    \
        _Pragma("unroll")                                                     \
        for (int i_ = 0; i_ < 16; ++i_) {                                     \
            outA[(size_t)i_ * NT * D + (size_t)(TS) * D + lane] =             \
                xT[0][lane * 17 + i_];                                        \
            outB[(size_t)i_ * NT * D + (size_t)(TS) * D + lane] =             \
                xT[1][lane * 17 + i_];                                        \
        }                                                                     \
    } while (0)

__global__ __launch_bounds__(64, 1)
void glv_rk4_mfma(const float* __restrict__ x0,
                  const float* __restrict__ r,
                  const float* __restrict__ A,
                  const float* __restrict__ tgrid,
                  float* __restrict__ out)
{
    const int lane = threadIdx.x & 63;
    const int g    = lane >> 4;
    const int p    = lane & 15;
    const int b0   = blockIdx.x * BW;          // G0: b0+p, G1: b0+16+p

    __shared__ float xT[2][D * 17];            // store-staging per group

    int dbase[4];
#pragma unroll
    for (int t = 0; t < 4; ++t) dbase[t] = 32 * (t >> 1) + 8 * g + 4 * (t & 1);

    // Stationary A-fragments of permuted E (E = A + I) — HW-verified layout.
    f16x8 af[4][2];
#pragma unroll
    for (int t = 0; t < 4; ++t) {
        const int rE = 32 * (t >> 1) + 8 * (p >> 2) + 4 * (t & 1) + (p & 3);
#pragma unroll
        for (int kh = 0; kh < 2; ++kh) {
            const int c0 = 32 * kh + 8 * g;
            const float4 v0 = *reinterpret_cast<const float4*>(A + rE * D + c0);
            const float4 v1 = *reinterpret_cast<const float4*>(A + rE * D + c0 + 4);
            float e[8] = {v0.x, v0.y, v0.z, v0.w, v1.x, v1.y, v1.z, v1.w};
#pragma unroll
            for (int j = 0; j < 8; ++j)
                if (rE == c0 + j) e[j] += 1.0f;
            union { uint32_t u[4]; f16x8 v; } un;
            un.u[0] = pkrtz(e[0], e[1]);
            un.u[1] = pkrtz(e[2], e[3]);
            un.u[2] = pkrtz(e[4], e[5]);
            un.u[3] = pkrtz(e[6], e[7]);
            af[t][kh] = un.v;
        }
    }
    // "+v" pins: keep af loop-resident in arch VGPRs (R10: "+a" regressed).
#pragma unroll
    for (int t = 0; t < 4; ++t)
#pragma unroll
        for (int kh = 0; kh < 2; ++kh)
            asm volatile("" : "+v"(af[t][kh]));

    // Shared r; per-group x0 in need-layout (dbase multiple of 4 -> f32x4).
    f32x4 rl[4], xA[4], xB[4];
#pragma unroll
    for (int t = 0; t < 4; ++t) {
        rl[t] = *reinterpret_cast<const f32x4*>(r + dbase[t]);
        xA[t] = *reinterpret_cast<const f32x4*>(x0 + (b0 + p) * D + dbase[t]);
        xB[t] = *reinterpret_cast<const f32x4*>(x0 + (b0 + 16 + p) * D + dbase[t]);
    }

    const float dt = tgrid[1] - tgrid[0];
    const float h2 = 0.5f * dt;
    const float h6 = dt * (1.0f / 6.0f);
    float* const outA = out + (size_t)b0 * NT * D;
    float* const outB = out + (size_t)(b0 + 16) * NT * D;

    STORE_STEP(0);                             // t = 0 output is x0

    f32x4 sA[4], sB[4], xsA[4], xsB[4], kA[4], kB[4];

    for (int ts = 1; ts < NT; ++ts) {
        FEVAL2(xA, kA, xB, kB);                        // k1
#pragma unroll
        for (int t = 0; t < 4; ++t) {                  // init s, stage2 input
            sA[t]  = xA[t] + vsplat(h6) * kA[t];
            xsA[t] = xA[t] + vsplat(h2) * kA[t];
            sB[t]  = xB[t] + vsplat(h6) * kB[t];
            xsB[t] = xB[t] + vsplat(h2) * kB[t];
        }
        FEVAL2(xsA, kA, xsB, kB);                      // k2
        COMB(xA, sA, xsA, kA, 2.0f * h6, h2)
        COMB(xB, sB, xsB, kB, 2.0f * h6, h2)
        FEVAL2(xsA, kA, xsB, kB);                      // k3
        COMB(xA, sA, xsA, kA, 2.0f * h6, dt)
        COMB(xB, sB, xsB, kB, 2.0f * h6, dt)
        FEVAL2(xsA, kA, xsB, kB);                      // k4
#pragma unroll
        for (int t = 0; t < 4; ++t) {
            xA[t] = sA[t] + vsplat(h6) * kA[t];
            xB[t] = sB[t] + vsplat(h6) * kB[t];
        }
        STORE_STEP(ts);
    }
}

extern "C" void kernel_launch(void* const* d_in, const int* in_sizes, int n_in,
                              void* d_out, int out_size, void* d_ws, size_t ws_size,
                              hipStream_t stream) {
    const float* x0    = (const float*)d_in[0];
    const float* r     = (const float*)d_in[1];
    const float* A     = (const float*)d_in[2];
    const float* tgrid = (const float*)d_in[3];
    float* out         = (float*)d_out;

    const int batch = in_sizes[0] / D;          // 2048
    dim3 grid(batch / BW);                      // 64 one-wave blocks
    dim3 block(64);

    glv_rk4_mfma<<<grid, block, 0, stream>>>(x0, r, A, tgrid, out);
}

// Round 12
// 249.035 us; speedup vs baseline: 2.2851x; 2.2851x over previous
//
#include <hip/hip_runtime.h>

// Generalized Lotka-Volterra, RK4, D=64, batch 2048, 255 steps,
// trajectory out (batch, 256, 64) fp32.
//
// Back to the 2048-wave (2 waves/SIMD) formulation — R11 proved the MFMA
// path is structurally capped at 128 blocks / ~270us. This round fuses the
// two best prior variants:
//   R4  (LDS f32 broadcast): lowest issue count, but 16KB LDS *return* per
//        feval per wave -> 480us return-path bound.
//   R6  (readlane+dot2):    no LDS, but ~79 issues/feval -> 302us issue-bound.
// Fusion: broadcast f16-PACKED x through LDS. Pack (x_2j, x_2j+1) with
// DPP-xor1 + v_cvt_pkrtz (2 ops), every lane does one ds_write_b32 (odd
// lanes land in a never-read shadow slot -> no divergence), then EIGHT
// uniform-address ds_read_b128 return the full 64-component f16 vector
// (8KB/feval/wave return, half of R4) into VGPRs, consumed by 16
// v_dot2_f32_f16 (VGPR,VGPR operands — no readlane, no SGPR hazards, no
// AGPR round-trips). ~34 issues/feval.
//   LDS-return floor: 2048 waves x 1020 fevals x 32 clk / 256 CU ~= 109us.
//   VALU:             ~65us, hides under LDS.
// Numerics: identical family to R5/R6 (E = A + I in f16 pairs, diagonal -x
// and growth r exact fp32) — passed at absmax 3.9e-3..5.9e-3.
//
// DS ordering: per-wave DS ops execute in order, so single-buffering is
// safe (next feval's write cannot pass this feval's reads). lgkmcnt(0)
// between write and reads makes the write visible wave-synchronously.

constexpr int D   = 64;   // state dimension == wavefront size
constexpr int NT  = 256;  // trajectory length (255 RK4 steps)
constexpr int WPB = 4;    // waves (= batch elements) per block

__device__ __forceinline__ uint32_t pkrtz(float lo, float hi) {
    return __builtin_bit_cast(uint32_t, __builtin_amdgcn_cvt_pkrtz(lo, hi));
}
// DPP xor-1 on a float (quad_perm [1,0,3,2]).
__device__ __forceinline__ float dpp_xor1(float v) {
    return __int_as_float(__builtin_amdgcn_update_dpp(
        0, __float_as_int(v), 0xB1, 0xF, 0xF, true));
}
// acc += dot2(e_pair, x_pair), both operands VGPR.
__device__ __forceinline__ float dot2v(float acc, uint32_t e, uint32_t x) {
    asm("v_dot2_f32_f16 %0, %1, %2, %0" : "+v"(acc) : "v"(e), "v"(x));
    return acc;
}

// f(xt) = xt * (r - xt + E@xt); broadcast via f16-packed LDS.
#define FEVAL(XT, RES)                                                        \
    do {                                                                      \
        const float xt_ = (XT);                                               \
        const uint32_t pair_ = pkrtz(xt_, dpp_xor1(xt_)); /* even lanes */    \
        wbuf[waddr] = pair_;                              /* 1 ds_write */    \
        asm volatile("s_waitcnt lgkmcnt(0)" ::: "memory");                    \
        float a0 = ri, a1 = 0.f, a2 = 0.f, a3 = 0.f;                          \
        _Pragma("unroll")                                                     \
        for (int J = 0; J < 8; ++J) {                     /* 8 uniform b128 */\
            const uint4 v_ = *reinterpret_cast<const uint4*>(wbuf + 4 * J);   \
            a0 = dot2v(a0, e[4 * J + 0], v_.x);                               \
            a1 = dot2v(a1, e[4 * J + 1], v_.y);                               \
            a2 = dot2v(a2, e[4 * J + 2], v_.z);                               \
            a3 = dot2v(a3, e[4 * J + 3], v_.w);                               \
        }                                                                     \
        RES = xt_ * (((a0 + a1) + (a2 + a3)) - xt_);                          \
    } while (0)

__global__ __launch_bounds__(WPB * 64, 2)
void glv_rk4_kernel(const float* __restrict__ x0,
                    const float* __restrict__ r,
                    const float* __restrict__ A,
                    const float* __restrict__ tgrid,
                    float* __restrict__ out)
{
    const int lane = threadIdx.x & 63;
    const int wid  = threadIdx.x >> 6;
    const int b    = blockIdx.x * WPB + wid;   // batch element for this wave

    // Per-wave broadcast buffer: 32 real pair-slots + 32 shadow (odd lanes).
    __shared__ uint32_t xf16[WPB][64];
    uint32_t* const wbuf = &xf16[wid][0];
    const int waddr = (lane >> 1) + (lane & 1) * 32;  // shadow for odd lanes

    // E = A + I, row `lane`, packed f16 pairs -> 32 VGPRs (one-time setup).
    uint32_t e[D / 2];
#pragma unroll
    for (int J = 0; J < D / 2; J += 2) {
        const float4 v = *reinterpret_cast<const float4*>(A + lane * D + 2 * J);
        const float e0 = v.x + ((2 * J)     == lane ? 1.0f : 0.0f);
        const float e1 = v.y + ((2 * J + 1) == lane ? 1.0f : 0.0f);
        const float e2 = v.z + ((2 * J + 2) == lane ? 1.0f : 0.0f);
        const float e3 = v.w + ((2 * J + 3) == lane ? 1.0f : 0.0f);
        e[J]     = pkrtz(e0, e1);
        e[J + 1] = pkrtz(e2, e3);
    }
    // Anti-sink fence: E stays VGPR-resident, loads can't sink into the loop.
#pragma unroll
    for (int J = 0; J < D / 2; ++J)
        asm volatile("" : "+v"(e[J]));

    const float ri = r[lane];
    const float dt = tgrid[1] - tgrid[0];
    const float h2 = 0.5f * dt;
    const float h6 = dt * (1.0f / 6.0f);

    float x = x0[(size_t)b * D + lane];

    float* o = out + (size_t)b * NT * D + lane;
    *o = x; o += D;                            // t = 0 is x0

    for (int t = 1; t < NT; ++t) {
        float k1, k2, k3, k4;
        FEVAL(x, k1);
        FEVAL(fmaf(h2, k1, x), k2);
        FEVAL(fmaf(h2, k2, x), k3);
        FEVAL(fmaf(dt, k3, x), k4);
        x = fmaf(h6, (k1 + k4) + 2.0f * (k2 + k3), x);
        *o = x; o += D;                        // coalesced 256 B/wave store
    }
}

extern "C" void kernel_launch(void* const* d_in, const int* in_sizes, int n_in,
                              void* d_out, int out_size, void* d_ws, size_t ws_size,
                              hipStream_t stream) {
    const float* x0    = (const float*)d_in[0];
    const float* r     = (const float*)d_in[1];
    const float* A     = (const float*)d_in[2];
    const float* tgrid = (const float*)d_in[3];
    float* out         = (float*)d_out;

    const int batch = in_sizes[0] / D;          // 2048
    dim3 grid(batch / WPB);                     // 512 blocks
    dim3 block(WPB * 64);                       // 256 threads = 4 waves

    glv_rk4_kernel<<<grid, block, 0, stream>>>(x0, r, A, tgrid, out);
}